// Round 11
// baseline (40.643 us; speedup 1.0000x reference)
//
#include <hip/hip_runtime.h>
#include <hip/hip_bf16.h>

#define D_ 128
#define S_ 512
#define B_ 4
#define H_ 8

typedef short bf16x8 __attribute__((ext_vector_type(8)));
typedef unsigned int u32x4 __attribute__((ext_vector_type(4)));
typedef float f32x4 __attribute__((ext_vector_type(4)));
typedef float f32x2 __attribute__((ext_vector_type(2)));

__device__ __forceinline__ short f2bf(float f) {
  __hip_bfloat16 h = __float2bfloat16(f);
  return __builtin_bit_cast(short, h);
}
__device__ __forceinline__ float fsigmoid(float x) {
  return __builtin_amdgcn_rcpf(1.0f + __expf(-x));
}
__device__ __forceinline__ unsigned int cvt_pk_bf16(float lo, float hi) {
  unsigned int r;
  asm("v_cvt_pk_bf16_f32 %0, %1, %2" : "=v"(r) : "v"(lo), "v"(hi));
  return r;
}

// Fused v2 (BISECT round): r10 with the a-path swapped MFMA -> VALU.
//  - a-path (NEW, simple): stage 8 i-rows f32 -> xi; each wave computes
//    a[8 rows][its 16 e-cols] by direct dot product; write alds (f32).
//  - C-path (r10's, under test): CHALF/CWRITE bf16 MFMA into cbf.
//  - main loop: r9 verbatim (verified, absmax 3.9e-3).
// If PASS -> r10's a-tile MFMA was the bug. If FAIL -> C-path is the bug.
__global__ __launch_bounds__(512, 4)
void fused_kernel(const float* __restrict__ x, const float* __restrict__ w1,
                  const float* __restrict__ b1, const float* __restrict__ w2,
                  const float* __restrict__ b2, float* __restrict__ out) {
  __shared__ short cbf[256 * D_];   // 64 KB: x j-half bf16, then C bf16
  __shared__ float xi[8 * D_];      // 4 KB: block's 8 i-rows, f32, plain
  __shared__ float alds[8 * D_];    // 4 KB: a rows (f32, b1 folded)

  const int t = threadIdx.x;
  const int lane = t & 63;
  const int wid = t >> 6;                // 0..7
  const int b  = blockIdx.x >> 7;
  const int jh = (blockIdx.x >> 6) & 1;
  const int ig = blockIdx.x & 63;
  const int i  = ig * 8 + wid;

  const int jcol = lane & 15;
  const int lgrp = lane >> 4;
  const int sw = jcol & 7;

  // ---- P0: stage x j-half -> cbf (bf16, swizzled); i-rows -> xi (f32)
  {
    const float* xb = x + (b * S_ + jh * 256) * D_;
    #pragma unroll
    for (int it = 0; it < 8; ++it) {
      int p = t + it * 512;
      int row = p >> 4, u = p & 15;
      const float* src = xb + row * D_ + u * 8;
      float4 v0 = *(const float4*)src;
      float4 v1 = *(const float4*)(src + 4);
      u32x4 w;
      w[0] = cvt_pk_bf16(v0.x, v0.y);
      w[1] = cvt_pk_bf16(v0.z, v0.w);
      w[2] = cvt_pk_bf16(v1.x, v1.y);
      w[3] = cvt_pk_bf16(v1.z, v1.w);
      *(u32x4*)(cbf + row * D_ + (u ^ (row & 7)) * 8) = w;
    }
    const float* xr = x + (size_t)(b * S_ + ig * 8 + wid) * D_;
    *(float2*)(xi + wid * D_ + lane * 2) = *(const float2*)(xr + lane * 2);
  }
  __syncthreads();                                   // W0

  // ---- a-path (VALU): wave wid -> e-col ec; lane covers rows r1, r1+4
  {
    const int ec = wid * 16 + (lane & 15);
    const int r1 = lane >> 4;              // 0..3
    float a0 = 0.f, a1 = 0.f;
    #pragma unroll 8
    for (int k = 0; k < D_; ++k) {
      float wv = w1[k * D_ + ec];
      a0 += xi[r1 * D_ + k] * wv;
      a1 += xi[(r1 + 4) * D_ + k] * wv;
    }
    float bb = b1[ec];
    alds[r1 * D_ + ec] = a0 + bb;
    alds[(r1 + 4) * D_ + ec] = a1 + bb;
  }

  const int eg = wid * 16 + jcol;          // this wave's e column (C-path)

  // w1c B-frags for this wave's e-tile (reused across all 16 j-tiles)
  bf16x8 w1cf[4];
  #pragma unroll
  for (int kc = 0; kc < 4; ++kc) {
    #pragma unroll
    for (int e = 0; e < 8; ++e)
      w1cf[kc][e] = f2bf(w1[(D_ + kc * 32 + lgrp * 8 + e) * D_ + eg]);
  }

  f32x4 dc[8];
  auto CHALF = [&](int jt0) {
    #pragma unroll
    for (int jt = 0; jt < 8; ++jt) {
      f32x4 acc = {0.f, 0.f, 0.f, 0.f};
      const short* bp = cbf + ((jt0 + jt) * 16 + jcol) * D_;
      #pragma unroll
      for (int kc = 0; kc < 4; ++kc) {
        u32x4 af = *(const u32x4*)(bp + (((kc * 4 + lgrp) ^ sw) * 8));
        acc = __builtin_amdgcn_mfma_f32_16x16x32_bf16(
            __builtin_bit_cast(bf16x8, af), w1cf[kc], acc, 0, 0, 0);
      }
      dc[jt] = acc;
    }
  };
  auto CWRITE = [&](int jt0) {
    const int u = eg >> 3, el = eg & 7;
    #pragma unroll
    for (int jt = 0; jt < 8; ++jt) {
      #pragma unroll
      for (int reg = 0; reg < 4; ++reg) {
        int row = (jt0 + jt) * 16 + lgrp * 4 + reg;
        cbf[row * D_ + ((u ^ (row & 7)) * 8) + el] = f2bf(dc[jt][reg]);
      }
    }
  };

  CHALF(0);                  // reads x tiles 0-7
  __syncthreads();           // W1
  CWRITE(0);                 // overwrite tiles 0-7 with C
  __syncthreads();           // W2
  CHALF(8);                  // reads x tiles 8-15 (untouched)
  __syncthreads();           // W3
  CWRITE(8);

  // ---- main-loop setup (r9 verbatim semantics)
  f32x2 apk[4][4];
  {
    const float* Ai = alds + wid * D_ + lgrp * 8;    // written pre-W1
    #pragma unroll
    for (int ch = 0; ch < 4; ++ch) {
      f32x4 v0 = *(const f32x4*)(Ai + ch * 32);
      f32x4 v1 = *(const f32x4*)(Ai + ch * 32 + 4);
      apk[ch][0][0] = v0[0]; apk[ch][0][1] = v0[1];
      apk[ch][1][0] = v0[2]; apk[ch][1][1] = v0[3];
      apk[ch][2][0] = v1[0]; apk[ch][2][1] = v1[1];
      apk[ch][3][0] = v1[2]; apk[ch][3][1] = v1[3];
    }
  }
  bf16x8 w2f[4];
  #pragma unroll
  for (int ch = 0; ch < 4; ++ch) {
    #pragma unroll
    for (int e = 0; e < 8; ++e) {
      float wv = (jcol < H_) ? w2[(ch * 32 + lgrp * 8 + e) * H_ + jcol] : 0.0f;
      w2f[ch][e] = f2bf(wv);
    }
  }
  const float b2v = (jcol < H_) ? b2[jcol] : 0.0f;
  float* outp = out + (((size_t)(b * H_ + (jcol & 7)) * S_ + i) * S_)
                + jh * 256 + lgrp * 4;
  __syncthreads();           // W4 — C fully materialized

  u32x4 cva[4], cvb[4];
  auto LOADT = [&](u32x4 (&dst)[4], int jt) {
    const short* bp = cbf + (jt * 16 + jcol) * D_;
    #pragma unroll
    for (int ch = 0; ch < 4; ++ch)
      dst[ch] = *(const u32x4*)(bp + (((ch * 4 + lgrp) ^ sw) * 8));
  };
  auto COMPUTE = [&](u32x4 (&cv)[4], int jt) {
    f32x4 acc = {0.f, 0.f, 0.f, 0.f};
    #pragma unroll
    for (int ch = 0; ch < 4; ++ch) {
      u32x4 hfd;
      #pragma unroll
      for (int p = 0; p < 4; ++p) {
        unsigned int d = cv[ch][p];
        f32x2 v;
        v[0] = __builtin_bit_cast(float, d << 16);
        v[1] = __builtin_bit_cast(float, d & 0xffff0000u);
        v += apk[ch][p];
        hfd[p] = cvt_pk_bf16(fmaxf(v[0], 0.f), fmaxf(v[1], 0.f));
      }
      bf16x8 hf = __builtin_bit_cast(bf16x8, hfd);
      acc = __builtin_amdgcn_mfma_f32_16x16x32_bf16(hf, w2f[ch], acc, 0, 0, 0);
    }
    if (jcol < H_) {
      float4 o;
      o.x = fsigmoid(acc[0] + b2v);
      o.y = fsigmoid(acc[1] + b2v);
      o.z = fsigmoid(acc[2] + b2v);
      o.w = fsigmoid(acc[3] + b2v);
      *(float4*)(outp + jt * 16) = o;
    }
  };

  LOADT(cva, 0);
  #pragma unroll 1
  for (int jt = 0; jt < 16; jt += 2) {
    LOADT(cvb, jt + 1);
    COMPUTE(cva, jt);
    LOADT(cva, (jt + 2) & 15);
    COMPUTE(cvb, jt + 1);
  }
}

extern "C" void kernel_launch(void* const* d_in, const int* in_sizes, int n_in,
                              void* d_out, int out_size, void* d_ws, size_t ws_size,
                              hipStream_t stream) {
  const float* x  = (const float*)d_in[0];
  const float* w1 = (const float*)d_in[1];
  const float* b1 = (const float*)d_in[2];
  const float* w2 = (const float*)d_in[3];
  const float* b2 = (const float*)d_in[4];
  float* out = (float*)d_out;
  fused_kernel<<<B_ * 2 * 64, 512, 0, stream>>>(x, w1, b1, w2, b2, out);
}